// Round 1
// 281.030 us; speedup vs baseline: 1.0066x; 1.0066x over previous
//
#include <hip/hip_runtime.h>

// MaskedEmbedding: out[t, :] = (mask_real[x[t], :] > THR ? weight[x[t], :] : 0)
// x: [B*S] int32, mask_real/weight: [VOCAB, D] fp32, out: [B*S, D] fp32.
//
// Structure: ONE WAVE PER TOKEN. 64 lanes x 3 float4 = 768 floats = one row.
// Each wave: 1 scalar x-load -> 6 independent coalesced 1KB global loads
// (3 mask + 3 weight) in flight simultaneously -> 3 non-temporal stores.
// Grid-stride at 2048 blocks x 256 threads (8 blocks/CU, 32 waves/CU).
// NT stores keep the write-once 48MB output from evicting the gather
// tables (touched rows ~86MB, L3-resident) out of L2/L3.

#define D_DIM 768
#define D4    (D_DIM / 4)   // 192 float4 per row
#define THR   0.01f

typedef float f4 __attribute__((ext_vector_type(4)));

__device__ __forceinline__ f4 sel(f4 m, f4 w) {
    f4 o;
    o.x = (m.x > THR) ? w.x : 0.0f;
    o.y = (m.y > THR) ? w.y : 0.0f;
    o.z = (m.z > THR) ? w.z : 0.0f;
    o.w = (m.w > THR) ? w.w : 0.0f;
    return o;
}

__global__ __launch_bounds__(256) void masked_embedding_kernel(
    const int* __restrict__ x,
    const f4*  __restrict__ mask,
    const f4*  __restrict__ weight,
    f4*        __restrict__ out,
    int n_tokens)
{
    const int lane   = threadIdx.x & 63;
    const int wid    = (blockIdx.x * blockDim.x + threadIdx.x) >> 6;   // global wave id
    const int nwaves = (gridDim.x * blockDim.x) >> 6;

    for (int token = wid; token < n_tokens; token += nwaves) {
        // Wave-uniform row index -> force scalar (SGPR) broadcast so the
        // 6 vector loads below share one scalar fetch, not 64 replicas.
        const int row = __builtin_amdgcn_readfirstlane(x[token]);

        const size_t base = (size_t)row   * D4 + lane;   // table offset (f4 units)
        const size_t ob   = (size_t)token * D4 + lane;   // output offset

        // 6 independent loads, each a fully-coalesced 1KB transaction.
        const f4 m0 = mask[base];
        const f4 m1 = mask[base + 64];
        const f4 m2 = mask[base + 128];
        const f4 w0 = weight[base];
        const f4 w1 = weight[base + 64];
        const f4 w2 = weight[base + 128];

        // Write-once output: non-temporal so it doesn't thrash L2/L3
        // capacity that the gather tables are using.
        __builtin_nontemporal_store(sel(m0, w0), &out[ob]);
        __builtin_nontemporal_store(sel(m1, w1), &out[ob + 64]);
        __builtin_nontemporal_store(sel(m2, w2), &out[ob + 128]);
    }
}

extern "C" void kernel_launch(void* const* d_in, const int* in_sizes, int n_in,
                              void* d_out, int out_size, void* d_ws, size_t ws_size,
                              hipStream_t stream)
{
    const int* x      = (const int*)d_in[0];    // [B*S]
    const f4*  mask   = (const f4*)d_in[1];     // [VOCAB, D]
    const f4*  weight = (const f4*)d_in[2];     // [VOCAB, D]
    f4*        out    = (f4*)d_out;             // [B*S, D]

    const int n_tokens = in_sizes[0];           // B*S = 16384

    // Memory-bound: cap grid at 2048 blocks (8/CU), grid-stride the rest.
    const int blocks = 2048;
    masked_embedding_kernel<<<blocks, 256, 0, stream>>>(x, mask, weight, out, n_tokens);
}